// Round 4
// baseline (505.649 us; speedup 1.0000x reference)
//
#include <hip/hip_runtime.h>
#include <hip/hip_bf16.h>

// Problem constants (match reference): K=4, B=4096, T=32, D=128
constexpr int K = 4;
constexpr int B = 4096;   // power of two: kb>>12 = k, kb&4095 = b
constexpr int T = 32;
constexpr int D = 128;
constexpr int TT = T * T;   // 1024 floats per anchor per pair-region
constexpr int TD = T * D;   // 4096 floats per anchor's nbr_embed

// metadata layout per anchor in d_ws (dwords): [0,32) nsim, [32,64) idx,
// [64] same-bits, pad to 80 (16B-aligned: 80*4=320B, 320%16==0)
constexpr int META = 80;

// f4 geometry of the flat output
constexpr size_t REG_F4   = (size_t)K * B * TT / 4;  // 4,194,304 per pair-region
constexpr size_t NBR_BASE = 3 * REG_F4;              // 12,582,912
constexpr size_t TOT_F4   = NBR_BASE + (size_t)K * B * TD / 4;  // 29,360,128
constexpr int    BLK_F4   = 2048;                    // 32KB contiguous per block
constexpr int    NBLOCKS  = (int)(TOT_F4 / BLK_F4);  // 14,336

typedef float f4 __attribute__((ext_vector_type(4)));

__device__ __forceinline__ float dot4(f4 a, f4 b) {
    return a.x * b.x + a.y * b.y + a.z * b.z + a.w * b.w;
}

// butterfly sum across the 32 lanes of a half-wave
__device__ __forceinline__ float hreduce32(float p) {
    #pragma unroll
    for (int m = 16; m >= 1; m >>= 1) p += __shfl_xor(p, m, 64);
    return p;
}

// ---------------------------------------------------------------------------
// K1: per-anchor metadata -> d_ws. One 256-thread block per anchor.
// Reads are L2-resident (2MB/domain semb); writes only 320B/anchor (5MB).
// ---------------------------------------------------------------------------
__global__ __launch_bounds__(256) void k_meta(
    const float* __restrict__ semb,     // [K,B,D]
    const int*   __restrict__ slabels,  // [K,B]
    const int*   __restrict__ topk,     // [K,B,T]
    float* __restrict__ ws)             // [K*B, META]
{
    const int kb  = blockIdx.x;
    const int k   = kb >> 12;
    const int tid = threadIdx.x;

    __shared__ f4    anchor4[T];
    __shared__ int   idx_s[T];
    __shared__ float nsim_s[T];

    const int my_label = slabels[kb];
    int same = 0;
    if (tid < T) {
        const int idx = topk[kb * T + tid];
        idx_s[tid] = idx;
        same = (slabels[(k << 12) + idx] == my_label) ? 1 : 0;
        anchor4[tid] =
            reinterpret_cast<const f4*>(semb + (size_t)kb * D)[tid];
    }
    const unsigned long long bal = __ballot(same);  // low 32 bits = mask (wave 0)
    __syncthreads();

    const f4* semb4 = reinterpret_cast<const f4*>(semb + (size_t)k * B * D);
    const int w  = tid >> 5;
    const int d4 = tid & 31;
    const f4  a  = anchor4[d4];
    const int i0 = idx_s[w], i1 = idx_s[8 + w], i2 = idx_s[16 + w], i3 = idx_s[24 + w];

    const f4 s0 = semb4[(size_t)i0 * (D / 4) + d4];
    const f4 s1 = semb4[(size_t)i1 * (D / 4) + d4];
    const f4 s2 = semb4[(size_t)i2 * (D / 4) + d4];
    const f4 s3 = semb4[(size_t)i3 * (D / 4) + d4];

    const float p0 = hreduce32(dot4(a, s0));
    const float p1 = hreduce32(dot4(a, s1));
    const float p2 = hreduce32(dot4(a, s2));
    const float p3 = hreduce32(dot4(a, s3));
    if (d4 == 0) {
        nsim_s[0  + w] = p0;
        nsim_s[8  + w] = p1;
        nsim_s[16 + w] = p2;
        nsim_s[24 + w] = p3;
    }
    __syncthreads();

    float* m = ws + (size_t)kb * META;
    if (tid < T) {
        m[tid] = nsim_s[tid];
        reinterpret_cast<int*>(m)[T + tid] = idx_s[tid];
    }
    if (tid == 32)  // wave 0, lane 32 holds bal
        reinterpret_cast<unsigned*>(m)[2 * T] = (unsigned)bal;
}

// ---------------------------------------------------------------------------
// K2: fill-shaped streamer. Each block owns one contiguous 32KB span of ONE
// output region (spans never straddle regions: 2048 | 4,194,304). Metadata
// reads are L1/L2 broadcasts; stores are long contiguous runs like the
// 6.3 TB/s fillBuffer yardstick.
// ---------------------------------------------------------------------------
__global__ __launch_bounds__(256) void k_stream(
    const float* __restrict__ semb,   // [K,B,D]
    const float* __restrict__ ws,     // [K*B, META]
    f4* __restrict__ out4)            // flat output as f4
{
    const int tid = threadIdx.x;
    const size_t g0 = (size_t)blockIdx.x * BLK_F4;

    if (g0 >= NBR_BASE) {
        // ---- nbr region: gather semb rows (L2-hit) -> 32KB stream ----
        const size_t n0 = g0 - NBR_BASE;
        const f4* semb4 = reinterpret_cast<const f4*>(semb);
        #pragma unroll
        for (int i = 0; i < 8; ++i) {
            const size_t n  = n0 + i * 256 + tid;
            const int    kb = (int)(n >> 10);          // 1024 f4 per anchor
            const int    q  = (int)(n & 1023);
            const int    t  = q >> 5;
            const int    d4 = q & 31;
            const int idx = reinterpret_cast<const int*>(ws + (size_t)kb * META)[T + t];
            const int k   = kb >> 12;
            const f4 v = semb4[(((size_t)(k << 12) + idx) * (D / 4)) + d4];
            out4[NBR_BASE + n] = v;
        }
        return;
    }

    const int    region = (int)(g0 / REG_F4);   // 0=pos 1=neg 2=mask (uniform)
    const size_t p0     = g0 % REG_F4;
    const int    kb0    = (int)(p0 >> 8);       // 256 f4 per anchor
    const int    s_row  = tid >> 3;
    const int    dq     = tid & 7;

    if (region == 0) {
        #pragma unroll
        for (int i = 0; i < 8; ++i) {
            const float* m = ws + (size_t)(kb0 + i) * META;
            const unsigned bits = reinterpret_cast<const unsigned*>(m)[2 * T];
            const int ss = (bits >> s_row) & 1;
            const unsigned ndb = ~(bits >> (dq * 4));
            const float ps = m[s_row];
            f4 v;
            v.x = (ss & (ndb & 1))        ? ps : 0.0f;
            v.y = (ss & ((ndb >> 1) & 1)) ? ps : 0.0f;
            v.z = (ss & ((ndb >> 2) & 1)) ? ps : 0.0f;
            v.w = (ss & ((ndb >> 3) & 1)) ? ps : 0.0f;
            out4[g0 + i * 256 + tid] = v;
        }
    } else if (region == 1) {
        #pragma unroll
        for (int i = 0; i < 8; ++i) {
            const float* m = ws + (size_t)(kb0 + i) * META;
            const unsigned bits = reinterpret_cast<const unsigned*>(m)[2 * T];
            const int ss = (bits >> s_row) & 1;
            const unsigned ndb = ~(bits >> (dq * 4));
            const f4 nd = reinterpret_cast<const f4*>(m)[dq];
            f4 v;
            v.x = (ss & (ndb & 1))        ? nd.x : 0.0f;
            v.y = (ss & ((ndb >> 1) & 1)) ? nd.y : 0.0f;
            v.z = (ss & ((ndb >> 2) & 1)) ? nd.z : 0.0f;
            v.w = (ss & ((ndb >> 3) & 1)) ? nd.w : 0.0f;
            out4[g0 + i * 256 + tid] = v;
        }
    } else {
        #pragma unroll
        for (int i = 0; i < 8; ++i) {
            const float* m = ws + (size_t)(kb0 + i) * META;
            const unsigned bits = reinterpret_cast<const unsigned*>(m)[2 * T];
            const int ss = (bits >> s_row) & 1;
            const unsigned ndb = ~(bits >> (dq * 4));
            f4 v;
            v.x = (float)(ss & (ndb & 1));
            v.y = (float)(ss & ((ndb >> 1) & 1));
            v.z = (float)(ss & ((ndb >> 2) & 1));
            v.w = (float)(ss & ((ndb >> 3) & 1));
            out4[g0 + i * 256 + tid] = v;
        }
    }
}

extern "C" void kernel_launch(void* const* d_in, const int* in_sizes, int n_in,
                              void* d_out, int out_size, void* d_ws, size_t ws_size,
                              hipStream_t stream) {
    const float* semb    = (const float*)d_in[0];
    const int*   slabels = (const int*)d_in[1];
    const int*   topk    = (const int*)d_in[2];
    float*       ws      = (float*)d_ws;     // needs 16384*320B = 5 MB

    k_meta<<<dim3(K * B), dim3(256), 0, stream>>>(semb, slabels, topk, ws);
    k_stream<<<dim3(NBLOCKS), dim3(256), 0, stream>>>(
        semb, ws, reinterpret_cast<f4*>(d_out));
}